// Round 1
// 356.939 us; speedup vs baseline: 1.0436x; 1.0436x over previous
//
#include <hip/hip_runtime.h>
#include <hip/hip_bf16.h>
#include <math.h>

#define NNODES 50000
#define NEDGES 800000
#define NGRAPH 64
#define FIN 128
#define HC 256     // H * HID
#define NHEAD 4
#define NOUT 10
#define ETOT (NEDGES + NNODES)   // edges + self-loops
#define NB196 ((NNODES + 255) / 256)   // 196 sort buckets
#define BCAP 5376                       // per-bucket capacity (15 sigma above mean 4337)
#define S1CHUNK 4096                    // edges per scatter1 block (16/thread)
#define NBS1 ((ETOT + S1CHUNK - 1) / S1CHUNK)   // 208

// Channel permutation σ (within each 64-channel head block):
//   stored p = (c & ~63) | ((c&15)<<2) | ((c>>4)&3)   [actual c -> stored p]
// Hb (fp8) and Ab (bf16) live in σ-layout; w2b/w3b K-dims σ-permuted at
// conversion; bias/Wl loads re-indexed; es/ed epilogue uses fp32 acc directly.

typedef unsigned short u16;
typedef unsigned char u8;
typedef __attribute__((ext_vector_type(8))) short short8;
typedef __attribute__((ext_vector_type(4))) float f32x4;
typedef __attribute__((ext_vector_type(2))) float f32x2;
typedef __attribute__((ext_vector_type(4))) unsigned uint4v;

__device__ inline u16 f2b(float f) {
    union { float f; unsigned u; } v; v.f = f;
    unsigned r = v.u + 0x7FFF + ((v.u >> 16) & 1);   // RNE (finite values)
    return (u16)(r >> 16);
}
__device__ inline float b2f(u16 u) {
    union { unsigned u; float f; } v; v.u = ((unsigned)u) << 16; return v.f;
}

__device__ inline void gload_lds16(const void* g, void* l) {
    __builtin_amdgcn_global_load_lds(
        (const __attribute__((address_space(1))) unsigned*)g,
        (__attribute__((address_space(3))) unsigned*)l, 16, 0, 0);
}

// ---------------- prep: bf16 conversions only (degree histogram removed; ----
// per-dst counts now derived in scatter2's LDS for free)

#define CS0 (NNODES * FIN)   // 6,400,000
#define CS1 (HC * FIN)       // 32,768
#define CS2 (HC * HC)        // 65,536
#define NBCONV (((CS0 + CS1 + 2 * CS2) / 4 + 255) / 256)   // 6410

__global__ void prep_kernel(const float* __restrict__ x, const float* __restrict__ W1,
                            const float* __restrict__ W2, const float* __restrict__ W3,
                            u16* __restrict__ xb, u16* __restrict__ w1b,
                            u16* __restrict__ w2b, u16* __restrict__ w3b) {
    int b = blockIdx.x;
    long i = (long)(b * 256 + threadIdx.x) * 4;
    if (i < CS0) {
        float4 v = *(const float4*)(x + i);
        ushort4 o;
        o.x = f2b(v.x); o.y = f2b(v.y); o.z = f2b(v.z); o.w = f2b(v.w);
        *(ushort4*)(xb + i) = o;
    } else if (i < CS0 + CS1) {
        long off = i - CS0;
        float4 v = *(const float4*)(W1 + off);
        ushort4 o;
        o.x = f2b(v.x); o.y = f2b(v.y); o.z = f2b(v.z); o.w = f2b(v.w);
        *(ushort4*)(w1b + off) = o;
    } else if (i < CS0 + CS1 + 2 * CS2) {
        const float* src; u16* dst; long off;
        if (i < CS0 + CS1 + CS2) { src = W2; dst = w2b; off = i - CS0 - CS1; }
        else                     { src = W3; dst = w3b; off = i - CS0 - CS1 - CS2; }
        float4 v = *(const float4*)(src + off);
        int row = (int)(off >> 8), col = (int)(off & 255);
        float vv[4] = {v.x, v.y, v.z, v.w};
        #pragma unroll
        for (int k = 0; k < 4; ++k) {
            int c = col + k;
            int pp = (c & ~63) | ((c & 15) << 2) | ((c >> 4) & 3);
            dst[row * 256 + pp] = f2b(vv[k]);
        }
    }
}

// ---------------- edge sort pass 1: block-aggregated atomics into fixed- ----
// capacity bucket slots (no prescan needed). 41k global atomics total.
// Packed u32: src (16b) | local-dst (8b) << 16.

__global__ __launch_bounds__(256) void scatter1_kernel(const int* __restrict__ ei,
                                                       int* __restrict__ bcur,
                                                       unsigned* __restrict__ tmp) {
    __shared__ int hist[NB196];
    __shared__ int basec[NB196];
    int tid = threadIdx.x;
    int e0 = blockIdx.x * S1CHUNK;
    for (int i = tid; i < NB196; i += 256) hist[i] = 0;
    __syncthreads();
    int bkt[16], rnk[16];
    unsigned pk[16];
    #pragma unroll
    for (int k = 0; k < 16; ++k) {
        int e = e0 + k * 256 + tid;
        bkt[k] = -1;
        if (e < ETOT) {
            int src, dstn;
            if (e < NEDGES) { src = ei[e]; dstn = ei[NEDGES + e]; }
            else            { src = dstn = e - NEDGES; }
            int b = dstn >> 8;
            bkt[k] = b;
            rnk[k] = atomicAdd(&hist[b], 1);
            pk[k] = (unsigned)src | ((unsigned)(dstn & 255) << 16);
        }
    }
    __syncthreads();
    for (int i = tid; i < NB196; i += 256) {
        int h = hist[i];
        basec[i] = h ? atomicAdd(&bcur[i], h) : 0;
    }
    __syncthreads();
    #pragma unroll
    for (int k = 0; k < 16; ++k) {
        if (bkt[k] >= 0) {
            int pos = basec[bkt[k]] + rnk[k];
            if (pos < BCAP)
                tmp[(size_t)bkt[k] * BCAP + pos] = pk[k];
        }
    }
}

// ---------------- bucket-total scan (196 values, 1 block) + graph offsets ----

__global__ __launch_bounds__(256) void scanb_kernel(const int* __restrict__ bcur,
                                                    int* __restrict__ bsum,
                                                    const int* __restrict__ batch,
                                                    int* __restrict__ goff) {
    int tid = threadIdx.x, lane = tid & 63, wid = tid >> 6;
    __shared__ int ws[4];
    int v = 0;
    if (tid < NB196) { v = bcur[tid]; if (v > BCAP) v = BCAP; }
    int x = v;
    #pragma unroll
    for (int o = 1; o < 64; o <<= 1) {
        int t = __shfl_up(x, o);
        if (lane >= o) x += t;
    }
    if (lane == 63) ws[wid] = x;
    __syncthreads();
    if (tid < 4) {
        int w = ws[tid];
        #pragma unroll
        for (int o = 1; o < 4; o <<= 1) {
            int t = __shfl_up(w, o, 4);
            if ((tid & 3) >= o) w += t;
        }
        ws[tid] = w;
    }
    __syncthreads();
    int wexcl = wid ? ws[wid - 1] : 0;
    if (tid <= NB196) bsum[tid] = x - v + wexcl;
    if (tid <= NGRAPH) {
        int g = tid, lo = 0, hi = NNODES;
        while (lo < hi) {
            int mid = (lo + hi) >> 1;
            if (batch[mid] < g) lo = mid + 1; else hi = mid;
        }
        goff[g] = lo;
    }
}

// ---------------- pass 2: one block per bucket. Stage bucket in LDS, count ----
// per-dst, block-scan 256 counters -> write off[] (within-bucket CSR), then
// rank+scatter in LDS, copy out coalesced. (Replaces prep's global-atomic
// degree histogram + scan1.)

__global__ __launch_bounds__(256) void scatter2_kernel(const unsigned* __restrict__ tmp,
                                                       const int* __restrict__ bcur,
                                                       const int* __restrict__ bsum,
                                                       int* __restrict__ off,
                                                       int* __restrict__ ssrc) {
    __shared__ unsigned ebuf[BCAP];
    __shared__ int ldss[BCAP];
    __shared__ int cnt[256];
    __shared__ int loff[256];
    __shared__ int ws[4];
    int b = blockIdx.x;
    int tid = threadIdx.x;
    int n = bcur[b];
    if (n > BCAP) n = BCAP;
    cnt[tid] = 0;
    const unsigned* tb = tmp + (size_t)b * BCAP;
    for (int i = tid; i < n; i += 256) ebuf[i] = tb[i];
    __syncthreads();
    for (int i = tid; i < n; i += 256) atomicAdd(&cnt[ebuf[i] >> 16], 1);
    __syncthreads();
    // block exclusive scan of cnt[256]
    int lane = tid & 63, wid = tid >> 6;
    int v = cnt[tid];
    int x = v;
    #pragma unroll
    for (int o = 1; o < 64; o <<= 1) {
        int t = __shfl_up(x, o);
        if (lane >= o) x += t;
    }
    if (lane == 63) ws[wid] = x;
    __syncthreads();
    if (tid < 4) {
        int w = ws[tid];
        #pragma unroll
        for (int o = 1; o < 4; o <<= 1) {
            int t = __shfl_up(w, o, 4);
            if ((tid & 3) >= o) w += t;
        }
        ws[tid] = w;
    }
    __syncthreads();
    int wexcl = wid ? ws[wid - 1] : 0;
    int excl = x - v + wexcl;
    loff[tid] = excl;
    off[b * 256 + tid] = excl;
    cnt[tid] = 0;
    __syncthreads();
    for (int i = tid; i < n; i += 256) {
        unsigned pk = ebuf[i];
        int ld = (int)(pk >> 16);
        int rank = atomicAdd(&cnt[ld], 1);
        ldss[loff[ld] + rank] = (int)(pk & 0xFFFFu);
    }
    __syncthreads();
    int s = bsum[b];
    for (int i = tid; i < n; i += 256) ssrc[s + i] = ldss[i];
}

// ---------------- bf16 MFMA GEMM + fused e_src/e_dst epilogue ----------------
// C[N,256] = A[N,K] @ B[256,K]^T. 128x128 tile, 4 waves, BK=32, unpadded LDS +
// global_load_lds(16B), single buffer (best of R6-R9). C is stored in fp8
// e4m3 σ-layout (aggregate is the ONLY consumer of C since the es/ed fusion).

#define TBM 128
#define TBN 128
#define TBK 32

__global__ __launch_bounds__(256) void gemm_mfma(const u16* __restrict__ A,
                                                 const u16* __restrict__ B,
                                                 u8* __restrict__ C, int K,
                                                 const float* __restrict__ asrc,
                                                 const float* __restrict__ adst,
                                                 float* __restrict__ es,
                                                 float* __restrict__ ed) {
    __shared__ u16 Als[TBM * TBK];   // 8 KB
    __shared__ u16 Bls[TBN * TBK];   // 8 KB
    int tid = threadIdx.x;
    int wave = tid >> 6, lane = tid & 63;
    int brow = blockIdx.x * TBM, bcol = blockIdx.y * TBN;
    int m_base = (wave >> 1) * 64, n_base = (wave & 1) * 64;
    int r0 = tid >> 2, kc = (tid & 3) * 8;
    int lquad = lane >> 4, l16 = lane & 15;

    f32x4 acc[4][4] = {};

    const u16* ga0 = A + (size_t)(brow + r0) * K + kc;
    const u16* ga1 = A + (size_t)(brow + 64 + r0) * K + kc;
    const u16* gb0 = B + (size_t)(bcol + r0) * K + kc;
    const u16* gb1 = B + (size_t)(bcol + 64 + r0) * K + kc;
    u16* la0 = &Als[r0 * TBK + kc];          // byte offset == tid*16 (wave-contiguous)
    u16* la1 = &Als[(64 + r0) * TBK + kc];
    u16* lb0 = &Bls[r0 * TBK + kc];
    u16* lb1 = &Bls[(64 + r0) * TBK + kc];

    for (int k0 = 0; k0 < K; k0 += TBK) {
        __syncthreads();
        gload_lds16(ga0 + k0, la0);
        gload_lds16(ga1 + k0, la1);
        gload_lds16(gb0 + k0, lb0);
        gload_lds16(gb1 + k0, lb1);
        __syncthreads();
        short8 fa[4], fb[4];
        #pragma unroll
        for (int i = 0; i < 4; ++i) {
            fa[i] = *(const short8*)(&Als[(m_base + i * 16 + l16) * TBK + lquad * 8]);
            fb[i] = *(const short8*)(&Bls[(n_base + i * 16 + l16) * TBK + lquad * 8]);
        }
        #pragma unroll
        for (int i = 0; i < 4; ++i)
            #pragma unroll
            for (int j = 0; j < 4; ++j)
                acc[i][j] = __builtin_amdgcn_mfma_f32_16x16x32_bf16(fa[i], fb[j], acc[i][j], 0, 0, 0);
    }

    // fp8 σ-layout C store: stored bytes n_base+l16*4+{0..3} = acc[i][0..3][r]
    #pragma unroll
    for (int i = 0; i < 4; ++i) {
        int rbase = brow + m_base + i * 16 + lquad * 4;
        #pragma unroll
        for (int r = 0; r < 4; ++r) {
            int row = rbase + r;
            if (row < NNODES) {
                int u = 0;
                u = __builtin_amdgcn_cvt_pk_fp8_f32(acc[i][0][r], acc[i][1][r], u, false);
                u = __builtin_amdgcn_cvt_pk_fp8_f32(acc[i][2][r], acc[i][3][r], u, true);
                *(int*)(C + (size_t)row * HC + bcol + n_base + l16 * 4) = u;
            }
        }
    }

    // fused attention-scalar epilogue (fp32 accumulators — full precision)
    int head = (bcol + n_base) >> 6;
    float asv[4], adv[4];
    #pragma unroll
    for (int j = 0; j < 4; ++j) {
        asv[j] = asrc[head * 64 + j * 16 + l16];
        adv[j] = adst[head * 64 + j * 16 + l16];
    }
    #pragma unroll
    for (int i = 0; i < 4; ++i) {
        #pragma unroll
        for (int r = 0; r < 4; ++r) {
            float ps = 0.f, pd = 0.f;
            #pragma unroll
            for (int j = 0; j < 4; ++j) {
                ps = fmaf(acc[i][j][r], asv[j], ps);
                pd = fmaf(acc[i][j][r], adv[j], pd);
            }
            #pragma unroll
            for (int o = 1; o < 16; o <<= 1) {
                ps += __shfl_xor(ps, o);
                pd += __shfl_xor(pd, o);
            }
            int row = brow + m_base + i * 16 + lquad * 4 + r;
            if (l16 == 0 && row < NNODES) {
                es[row * 4 + head] = ps;
                ed[row * 4 + head] = pd;
            }
        }
    }
}

// ---------------- aggregate: 4 dst/block (1/wave); dwordx4 fp8 gathers with ----
// 4 edges in parallel across lane-groups; single fully-unrolled masked loop
// (inactive slots carry exj=0 and gather the L1-hot row 0).
// Consumer layout: g=lane>>4 edge subgroup, q=lane&15 covers stored bytes
// q*16..q*16+15 (one head: q>>2). Producer layout unchanged (head=lane>>4,
// edge=lane&15) for es/ed gathers and the per-head denominator.

__global__ __launch_bounds__(256) void aggregate_kernel(const u8* __restrict__ h,
                                                        const int* __restrict__ ssrc,
                                                        const int* __restrict__ off,
                                                        const int* __restrict__ bsum,
                                                        const float* __restrict__ es,
                                                        const float* __restrict__ ed,
                                                        const float* __restrict__ bias,
                                                        u16* __restrict__ out,
                                                        int apply_elu) {
    __shared__ int2 xch[4][4][17];   // [wave][head][16 edges + pad]
    const uint4v* h128 = (const uint4v*)h;   // 16 uint4 per σ-layout row
    int wid = threadIdx.x >> 6;
    int dst = blockIdx.x * 4 + wid;
    if (dst >= NNODES) return;
    int lane = threadIdx.x & 63;
    int headp = lane >> 4;     // producer head
    int j16 = lane & 15;       // producer edge slot
    int g = lane >> 4;         // consumer edge subgroup
    int q = lane & 15;         // consumer channel quad (stored bytes q*16..+15)
    int headc = q >> 2;        // consumer head
    int s = off[dst] + bsum[dst >> 8];
    int e = off[dst + 1] + bsum[(dst + 1) >> 8];
    float edh = ed[dst * 4 + headp];
    int2* pslot = &xch[wid][headp][0];
    const int2* cslot = &xch[wid][headc][0];

    float acc[16] = {};
    float dpriv = 0.f;

    for (int base = s; base < e; base += 16) {
        int cnt = e - base;
        if (cnt > 16) cnt = 16;
        int mysrc = 0;
        float myex = 0.f;
        if (j16 < cnt) {
            mysrc = ssrc[base + j16];
            float l = es[mysrc * 4 + headp] + edh;
            l = fmaxf(l, 0.2f * l);
            myex = __expf(l);
            dpriv += myex;
        }
        pslot[j16] = make_int2(mysrc, __float_as_int(myex));
        #pragma unroll
        for (int j = 0; j < 4; ++j) {
            if (j * 4 >= cnt) break;          // wave-uniform (cnt per-dst)
            int2 pr = cslot[j * 4 + g];
            float exj = __int_as_float(pr.y);
            uint4v hv = h128[(((unsigned)pr.x) << 4) + (unsigned)q];
            #pragma unroll
            for (int u = 0; u < 4; ++u) {
                f32x2 lo = __builtin_amdgcn_cvt_pk_f32_fp8(hv[u], false);
                f32x2 hi = __builtin_amdgcn_cvt_pk_f32_fp8(hv[u], true);
                acc[u * 4 + 0] += lo.x * exj;
                acc[u * 4 + 1] += lo.y * exj;
                acc[u * 4 + 2] += hi.x * exj;
                acc[u * 4 + 3] += hi.y * exj;
            }
        }
    }

    // per-head denominator (producer layout), broadcast to consumer layout
    #pragma unroll
    for (int o = 1; o < 16; o <<= 1) dpriv += __shfl_xor(dpriv, o);
    float inv = 1.f / (dpriv + 1e-16f);
    float invc = __shfl(inv, headc << 4);

    // reduce-scatter across the 4 edge subgroups: end with acc[0..3] holding
    // channels k = g*4+{0..3} fully summed (static indices only — no scratch)
    #pragma unroll
    for (int k = 0; k < 8; ++k) {
        float snd = (lane & 32) ? acc[k] : acc[k + 8];
        float rcv = __shfl_xor(snd, 32);
        if (lane & 32) acc[k + 8] += rcv; else acc[k] += rcv;
    }
    #pragma unroll
    for (int k = 0; k < 8; ++k)
        if (lane & 32) acc[k] = acc[k + 8];
    #pragma unroll
    for (int k = 0; k < 4; ++k) {
        float snd = (lane & 16) ? acc[k] : acc[k + 4];
        float rcv = __shfl_xor(snd, 16);
        if (lane & 16) acc[k + 4] += rcv; else acc[k] += rcv;
    }
    #pragma unroll
    for (int k = 0; k < 4; ++k)
        if (lane & 16) acc[k] = acc[k + 4];

    // epilogue: stored p = q*16 + g*4 + kd  ->  actual c = headc*64 + (q&3)*4 + g + kd*16
    int cbase = headc * 64 + (q & 3) * 4 + g;
    float o0 = acc[0] * invc + bias[cbase];
    float o1 = acc[1] * invc + bias[cbase + 16];
    float o2 = acc[2] * invc + bias[cbase + 32];
    float o3 = acc[3] * invc + bias[cbase + 48];
    if (apply_elu) {
        o0 = o0 > 0.f ? o0 : __expf(o0) - 1.f;
        o1 = o1 > 0.f ? o1 : __expf(o1) - 1.f;
        o2 = o2 > 0.f ? o2 : __expf(o2) - 1.f;
        o3 = o3 > 0.f ? o3 : __expf(o3) - 1.f;
    }
    ushort4 ov;
    ov.x = f2b(o0); ov.y = f2b(o1); ov.z = f2b(o2); ov.w = f2b(o3);
    *(ushort4*)(out + (size_t)dst * HC + q * 16 + g * 4) = ov;
}

// ---------------- sliced mean-pool partials: block = (graph, 8 node-slices) ----------------

__global__ __launch_bounds__(256) void pool_kernel(const u16* __restrict__ hin,
                                                   const int* __restrict__ goff,
                                                   float* __restrict__ pp) {
    int g = blockIdx.x;
    int slice = blockIdx.y;            // 0..7
    int lane = threadIdx.x & 63;
    int wid = threadIdx.x >> 6;
    int s = goff[g], e = goff[g + 1];
    float a0 = 0.f, a1 = 0.f, a2 = 0.f, a3 = 0.f;
    for (int n = s + slice * 4 + wid; n < e; n += 32) {
        ushort4 hv = *(const ushort4*)(hin + (size_t)n * HC + lane * 4);
        a0 += b2f(hv.x); a1 += b2f(hv.y); a2 += b2f(hv.z); a3 += b2f(hv.w);
    }
    __shared__ float4 part[4][64];
    part[wid][lane] = make_float4(a0, a1, a2, a3);
    __syncthreads();
    if (wid == 0) {
        float4 p0 = part[0][lane], p1 = part[1][lane], p2 = part[2][lane], p3 = part[3][lane];
        float4 v = make_float4((p0.x + p1.x) + (p2.x + p3.x),
                               (p0.y + p1.y) + (p2.y + p3.y),
                               (p0.z + p1.z) + (p2.z + p3.z),
                               (p0.w + p1.w) + (p2.w + p3.w));
        *(float4*)(pp + ((size_t)(g * 8 + slice)) * HC + lane * 4) = v;
    }
}

// ---------------- final classifier: sum 8 slice-partials, mean, Wl dot ----------------

__global__ __launch_bounds__(64) void final_kernel(const float* __restrict__ pp,
                                                   const int* __restrict__ goff,
                                                   const float* __restrict__ Wl,
                                                   const float* __restrict__ bl,
                                                   float* __restrict__ out) {
    int g = blockIdx.x;
    int lane = threadIdx.x;
    float4 pv = make_float4(0.f, 0.f, 0.f, 0.f);
    #pragma unroll
    for (int sl = 0; sl < 8; ++sl) {
        float4 v = *(const float4*)(pp + ((size_t)(g * 8 + sl)) * HC + lane * 4);
        pv.x += v.x; pv.y += v.y; pv.z += v.z; pv.w += v.w;
    }
    float cntf = fmaxf((float)(goff[g + 1] - goff[g]), 1.f);
    float inv = 1.f / cntf;
    pv.x *= inv; pv.y *= inv; pv.z *= inv; pv.w *= inv;
    int wbase = ((lane >> 4) << 6) | (lane & 15);             // actual ch = wbase+{0,16,32,48}
    float acc[NOUT];
    #pragma unroll
    for (int o = 0; o < NOUT; ++o) {
        const float* w = Wl + o * HC + wbase;
        acc[o] = pv.x * w[0] + pv.y * w[16] + pv.z * w[32] + pv.w * w[48];
    }
    #pragma unroll
    for (int s = 32; s > 0; s >>= 1)
        #pragma unroll
        for (int o = 0; o < NOUT; ++o)
            acc[o] += __shfl_xor(acc[o], s);
    if (lane == 0) {
        #pragma unroll
        for (int o = 0; o < NOUT; ++o)
            out[g * NOUT + o] = acc[o] + bl[o];
    }
}

// ---------------- launch ----------------

extern "C" void kernel_launch(void* const* d_in, const int* in_sizes, int n_in,
                              void* d_out, int out_size, void* d_ws, size_t ws_size,
                              hipStream_t stream) {
    (void)in_sizes; (void)n_in; (void)out_size; (void)ws_size;
    const float* x   = (const float*)d_in[0];
    const int*   ei  = (const int*)d_in[1];
    const int*   bat = (const int*)d_in[2];
    const float* W1  = (const float*)d_in[3];
    const float* as1 = (const float*)d_in[4];
    const float* ad1 = (const float*)d_in[5];
    const float* b1  = (const float*)d_in[6];
    const float* W2  = (const float*)d_in[7];
    const float* as2 = (const float*)d_in[8];
    const float* ad2 = (const float*)d_in[9];
    const float* b2  = (const float*)d_in[10];
    const float* W3  = (const float*)d_in[11];
    const float* as3 = (const float*)d_in[12];
    const float* ad3 = (const float*)d_in[13];
    const float* b3  = (const float*)d_in[14];
    const float* Wl  = (const float*)d_in[15];
    const float* bl  = (const float*)d_in[16];
    float* out = (float*)d_out;

    char* ws = (char*)d_ws;
    size_t p = 0;
    auto alloc = [&](size_t bytes) {
        size_t a = p;
        p += (bytes + 255) & ~(size_t)255;
        return a;
    };
    int*      off  = (int*)(ws + alloc((size_t)(NB196 * 256 + 256) * 4));
    int*      bcur = (int*)(ws + alloc(256 * 4));
    int*      ssrc = (int*)(ws + alloc((size_t)ETOT * 4));
    unsigned* tmp  = (unsigned*)(ws + alloc((size_t)NB196 * BCAP * 4));
    int*      bsum = (int*)(ws + alloc(256 * 4));
    float*    es   = (float*)(ws + alloc((size_t)NNODES * NHEAD * 4));
    float*    ed   = (float*)(ws + alloc((size_t)NNODES * NHEAD * 4));
    u16*      xb   = (u16*)(ws + alloc((size_t)NNODES * FIN * 2));
    u16*      w1b  = (u16*)(ws + alloc((size_t)HC * FIN * 2));
    u16*      w2b  = (u16*)(ws + alloc((size_t)HC * HC * 2));
    u16*      w3b  = (u16*)(ws + alloc((size_t)HC * HC * 2));
    u8*       Hb   = (u8*)(ws + alloc((size_t)NNODES * HC));       // fp8 e4m3, σ-layout
    u16*      Ab   = (u16*)(ws + alloc((size_t)NNODES * HC * 2));  // bf16, σ-layout
    float*    pp   = (float*)(ws + alloc((size_t)NGRAPH * 8 * HC * 4));   // pool partials
    int*      goff = (int*)(ws + alloc((size_t)(NGRAPH + 1) * 4));
    alloc(128 * 1024);   // slack: gemm A-tile over-read past row NNODES stays in d_ws

    // zero only the 196 bucket counters (deg histogram is gone)
    hipMemsetAsync(bcur, 0, 256 * 4, stream);

    // bf16/σ conversions
    prep_kernel<<<NBCONV, 256, 0, stream>>>(x, W1, W2, W3, xb, w1b, w2b, w3b);

    // counting sort of edges by dst (fixed-capacity buckets; off derived in pass 2)
    scatter1_kernel<<<NBS1, 256, 0, stream>>>(ei, bcur, tmp);
    scanb_kernel<<<1, 256, 0, stream>>>(bcur, bsum, bat, goff);
    scatter2_kernel<<<NB196, 256, 0, stream>>>(tmp, bcur, bsum, off, ssrc);

    dim3 ggrid((NNODES + TBM - 1) / TBM, HC / TBN);
    int nblocks4 = (NNODES + 3) / 4;

    // layer 1
    gemm_mfma<<<ggrid, 256, 0, stream>>>(xb, w1b, Hb, FIN, as1, ad1, es, ed);
    aggregate_kernel<<<nblocks4, 256, 0, stream>>>(Hb, ssrc, off, bsum, es, ed, b1, Ab, 1);
    // layer 2
    gemm_mfma<<<ggrid, 256, 0, stream>>>(Ab, w2b, Hb, HC, as2, ad2, es, ed);
    aggregate_kernel<<<nblocks4, 256, 0, stream>>>(Hb, ssrc, off, bsum, es, ed, b2, Ab, 1);
    // layer 3
    gemm_mfma<<<ggrid, 256, 0, stream>>>(Ab, w3b, Hb, HC, as3, ad3, es, ed);
    aggregate_kernel<<<nblocks4, 256, 0, stream>>>(Hb, ssrc, off, bsum, es, ed, b3, Ab, 0);

    // pool + classify
    dim3 pgrid(NGRAPH, 8);
    pool_kernel<<<pgrid, 256, 0, stream>>>(Ab, goff, pp);
    final_kernel<<<NGRAPH, 64, 0, stream>>>(pp, goff, Wl, bl, out);
}

// Round 2
// 338.736 us; speedup vs baseline: 1.0997x; 1.0537x over previous
//
#include <hip/hip_runtime.h>
#include <hip/hip_bf16.h>
#include <math.h>

#define NNODES 50000
#define NEDGES 800000
#define NGRAPH 64
#define FIN 128
#define HC 256     // H * HID
#define NHEAD 4
#define NOUT 10
#define ETOT (NEDGES + NNODES)   // edges + self-loops
#define NB196 ((NNODES + 255) / 256)   // 196 sort buckets
#define BCAP 5376                       // per-bucket capacity (15 sigma above mean 4337)
#define S1CHUNK 4096                    // edges per scatter1 block (16/thread)
#define NBS1 ((ETOT + S1CHUNK - 1) / S1CHUNK)   // 208

// Channel permutation σ (within each 64-channel head block):
//   stored p = (c & ~63) | ((c&15)<<2) | ((c>>4)&3)   [actual c -> stored p]
// Hb (fp8) and Ab (bf16) live in σ-layout; w2b/w3b K-dims σ-permuted at
// conversion; bias/Wl loads re-indexed; es/ed epilogue uses fp32 acc directly.

typedef unsigned short u16;
typedef unsigned char u8;
typedef __attribute__((ext_vector_type(8))) short short8;
typedef __attribute__((ext_vector_type(4))) float f32x4;
typedef __attribute__((ext_vector_type(2))) float f32x2;

__device__ inline u16 f2b(float f) {
    union { float f; unsigned u; } v; v.f = f;
    unsigned r = v.u + 0x7FFF + ((v.u >> 16) & 1);   // RNE (finite values)
    return (u16)(r >> 16);
}
__device__ inline float b2f(u16 u) {
    union { unsigned u; float f; } v; v.u = ((unsigned)u) << 16; return v.f;
}

__device__ inline void gload_lds16(const void* g, void* l) {
    __builtin_amdgcn_global_load_lds(
        (const __attribute__((address_space(1))) unsigned*)g,
        (__attribute__((address_space(3))) unsigned*)l, 16, 0, 0);
}

// ---------------- prep: bf16 conversions only ----------------

#define CS0 (NNODES * FIN)   // 6,400,000
#define CS1 (HC * FIN)       // 32,768
#define CS2 (HC * HC)        // 65,536
#define NBCONV (((CS0 + CS1 + 2 * CS2) / 4 + 255) / 256)   // 6410

__global__ void prep_kernel(const float* __restrict__ x, const float* __restrict__ W1,
                            const float* __restrict__ W2, const float* __restrict__ W3,
                            u16* __restrict__ xb, u16* __restrict__ w1b,
                            u16* __restrict__ w2b, u16* __restrict__ w3b) {
    int b = blockIdx.x;
    long i = (long)(b * 256 + threadIdx.x) * 4;
    if (i < CS0) {
        float4 v = *(const float4*)(x + i);
        ushort4 o;
        o.x = f2b(v.x); o.y = f2b(v.y); o.z = f2b(v.z); o.w = f2b(v.w);
        *(ushort4*)(xb + i) = o;
    } else if (i < CS0 + CS1) {
        long off = i - CS0;
        float4 v = *(const float4*)(W1 + off);
        ushort4 o;
        o.x = f2b(v.x); o.y = f2b(v.y); o.z = f2b(v.z); o.w = f2b(v.w);
        *(ushort4*)(w1b + off) = o;
    } else if (i < CS0 + CS1 + 2 * CS2) {
        const float* src; u16* dst; long off;
        if (i < CS0 + CS1 + CS2) { src = W2; dst = w2b; off = i - CS0 - CS1; }
        else                     { src = W3; dst = w3b; off = i - CS0 - CS1 - CS2; }
        float4 v = *(const float4*)(src + off);
        int row = (int)(off >> 8), col = (int)(off & 255);
        float vv[4] = {v.x, v.y, v.z, v.w};
        #pragma unroll
        for (int k = 0; k < 4; ++k) {
            int c = col + k;
            int pp = (c & ~63) | ((c & 15) << 2) | ((c >> 4) & 3);
            dst[row * 256 + pp] = f2b(vv[k]);
        }
    }
}

// ---------------- edge sort pass 1: block-aggregated atomics into fixed- ----
// capacity bucket slots (no prescan needed). 41k global atomics total.
// Packed u32: src (16b) | local-dst (8b) << 16.

__global__ __launch_bounds__(256) void scatter1_kernel(const int* __restrict__ ei,
                                                       int* __restrict__ bcur,
                                                       unsigned* __restrict__ tmp) {
    __shared__ int hist[NB196];
    __shared__ int basec[NB196];
    int tid = threadIdx.x;
    int e0 = blockIdx.x * S1CHUNK;
    for (int i = tid; i < NB196; i += 256) hist[i] = 0;
    __syncthreads();
    int bkt[16], rnk[16];
    unsigned pk[16];
    #pragma unroll
    for (int k = 0; k < 16; ++k) {
        int e = e0 + k * 256 + tid;
        bkt[k] = -1;
        if (e < ETOT) {
            int src, dstn;
            if (e < NEDGES) { src = ei[e]; dstn = ei[NEDGES + e]; }
            else            { src = dstn = e - NEDGES; }
            int b = dstn >> 8;
            bkt[k] = b;
            rnk[k] = atomicAdd(&hist[b], 1);
            pk[k] = (unsigned)src | ((unsigned)(dstn & 255) << 16);
        }
    }
    __syncthreads();
    for (int i = tid; i < NB196; i += 256) {
        int h = hist[i];
        basec[i] = h ? atomicAdd(&bcur[i], h) : 0;
    }
    __syncthreads();
    #pragma unroll
    for (int k = 0; k < 16; ++k) {
        if (bkt[k] >= 0) {
            int pos = basec[bkt[k]] + rnk[k];
            if (pos < BCAP)
                tmp[(size_t)bkt[k] * BCAP + pos] = pk[k];
        }
    }
}

// ---------------- bucket-total scan (196 values, 1 block) + graph offsets ----

__global__ __launch_bounds__(256) void scanb_kernel(const int* __restrict__ bcur,
                                                    int* __restrict__ bsum,
                                                    const int* __restrict__ batch,
                                                    int* __restrict__ goff) {
    int tid = threadIdx.x, lane = tid & 63, wid = tid >> 6;
    __shared__ int ws[4];
    int v = 0;
    if (tid < NB196) { v = bcur[tid]; if (v > BCAP) v = BCAP; }
    int x = v;
    #pragma unroll
    for (int o = 1; o < 64; o <<= 1) {
        int t = __shfl_up(x, o);
        if (lane >= o) x += t;
    }
    if (lane == 63) ws[wid] = x;
    __syncthreads();
    if (tid < 4) {
        int w = ws[tid];
        #pragma unroll
        for (int o = 1; o < 4; o <<= 1) {
            int t = __shfl_up(w, o, 4);
            if ((tid & 3) >= o) w += t;
        }
        ws[tid] = w;
    }
    __syncthreads();
    int wexcl = wid ? ws[wid - 1] : 0;
    if (tid <= NB196) bsum[tid] = x - v + wexcl;
    if (tid <= NGRAPH) {
        int g = tid, lo = 0, hi = NNODES;
        while (lo < hi) {
            int mid = (lo + hi) >> 1;
            if (batch[mid] < g) lo = mid + 1; else hi = mid;
        }
        goff[g] = lo;
    }
}

// ---------------- pass 2: one block per bucket. Stage bucket in LDS, count ----
// per-dst, block-scan 256 counters -> write off[] (within-bucket CSR), then
// rank+scatter in LDS, copy out coalesced.

__global__ __launch_bounds__(256) void scatter2_kernel(const unsigned* __restrict__ tmp,
                                                       const int* __restrict__ bcur,
                                                       const int* __restrict__ bsum,
                                                       int* __restrict__ off,
                                                       int* __restrict__ ssrc) {
    __shared__ unsigned ebuf[BCAP];
    __shared__ int ldss[BCAP];
    __shared__ int cnt[256];
    __shared__ int loff[256];
    __shared__ int ws[4];
    int b = blockIdx.x;
    int tid = threadIdx.x;
    int n = bcur[b];
    if (n > BCAP) n = BCAP;
    cnt[tid] = 0;
    const unsigned* tb = tmp + (size_t)b * BCAP;
    for (int i = tid; i < n; i += 256) ebuf[i] = tb[i];
    __syncthreads();
    for (int i = tid; i < n; i += 256) atomicAdd(&cnt[ebuf[i] >> 16], 1);
    __syncthreads();
    // block exclusive scan of cnt[256]
    int lane = tid & 63, wid = tid >> 6;
    int v = cnt[tid];
    int x = v;
    #pragma unroll
    for (int o = 1; o < 64; o <<= 1) {
        int t = __shfl_up(x, o);
        if (lane >= o) x += t;
    }
    if (lane == 63) ws[wid] = x;
    __syncthreads();
    if (tid < 4) {
        int w = ws[tid];
        #pragma unroll
        for (int o = 1; o < 4; o <<= 1) {
            int t = __shfl_up(w, o, 4);
            if ((tid & 3) >= o) w += t;
        }
        ws[tid] = w;
    }
    __syncthreads();
    int wexcl = wid ? ws[wid - 1] : 0;
    int excl = x - v + wexcl;
    loff[tid] = excl;
    off[b * 256 + tid] = excl;
    cnt[tid] = 0;
    __syncthreads();
    for (int i = tid; i < n; i += 256) {
        unsigned pk = ebuf[i];
        int ld = (int)(pk >> 16);
        int rank = atomicAdd(&cnt[ld], 1);
        ldss[loff[ld] + rank] = (int)(pk & 0xFFFFu);
    }
    __syncthreads();
    int s = bsum[b];
    for (int i = tid; i < n; i += 256) ssrc[s + i] = ldss[i];
}

// ---------------- bf16 MFMA GEMM + fused e_src/e_dst epilogue ----------------

#define TBM 128
#define TBN 128
#define TBK 32

__global__ __launch_bounds__(256) void gemm_mfma(const u16* __restrict__ A,
                                                 const u16* __restrict__ B,
                                                 u8* __restrict__ C, int K,
                                                 const float* __restrict__ asrc,
                                                 const float* __restrict__ adst,
                                                 float* __restrict__ es,
                                                 float* __restrict__ ed) {
    __shared__ u16 Als[TBM * TBK];   // 8 KB
    __shared__ u16 Bls[TBN * TBK];   // 8 KB
    int tid = threadIdx.x;
    int wave = tid >> 6, lane = tid & 63;
    int brow = blockIdx.x * TBM, bcol = blockIdx.y * TBN;
    int m_base = (wave >> 1) * 64, n_base = (wave & 1) * 64;
    int r0 = tid >> 2, kc = (tid & 3) * 8;
    int lquad = lane >> 4, l16 = lane & 15;

    f32x4 acc[4][4] = {};

    const u16* ga0 = A + (size_t)(brow + r0) * K + kc;
    const u16* ga1 = A + (size_t)(brow + 64 + r0) * K + kc;
    const u16* gb0 = B + (size_t)(bcol + r0) * K + kc;
    const u16* gb1 = B + (size_t)(bcol + 64 + r0) * K + kc;
    u16* la0 = &Als[r0 * TBK + kc];          // byte offset == tid*16 (wave-contiguous)
    u16* la1 = &Als[(64 + r0) * TBK + kc];
    u16* lb0 = &Bls[r0 * TBK + kc];
    u16* lb1 = &Bls[(64 + r0) * TBK + kc];

    for (int k0 = 0; k0 < K; k0 += TBK) {
        __syncthreads();
        gload_lds16(ga0 + k0, la0);
        gload_lds16(ga1 + k0, la1);
        gload_lds16(gb0 + k0, lb0);
        gload_lds16(gb1 + k0, lb1);
        __syncthreads();
        short8 fa[4], fb[4];
        #pragma unroll
        for (int i = 0; i < 4; ++i) {
            fa[i] = *(const short8*)(&Als[(m_base + i * 16 + l16) * TBK + lquad * 8]);
            fb[i] = *(const short8*)(&Bls[(n_base + i * 16 + l16) * TBK + lquad * 8]);
        }
        #pragma unroll
        for (int i = 0; i < 4; ++i)
            #pragma unroll
            for (int j = 0; j < 4; ++j)
                acc[i][j] = __builtin_amdgcn_mfma_f32_16x16x32_bf16(fa[i], fb[j], acc[i][j], 0, 0, 0);
    }

    // fp8 σ-layout C store: stored bytes n_base+l16*4+{0..3} = acc[i][0..3][r]
    #pragma unroll
    for (int i = 0; i < 4; ++i) {
        int rbase = brow + m_base + i * 16 + lquad * 4;
        #pragma unroll
        for (int r = 0; r < 4; ++r) {
            int row = rbase + r;
            if (row < NNODES) {
                int u = 0;
                u = __builtin_amdgcn_cvt_pk_fp8_f32(acc[i][0][r], acc[i][1][r], u, false);
                u = __builtin_amdgcn_cvt_pk_fp8_f32(acc[i][2][r], acc[i][3][r], u, true);
                *(int*)(C + (size_t)row * HC + bcol + n_base + l16 * 4) = u;
            }
        }
    }

    // fused attention-scalar epilogue (fp32 accumulators — full precision)
    int head = (bcol + n_base) >> 6;
    float asv[4], adv[4];
    #pragma unroll
    for (int j = 0; j < 4; ++j) {
        asv[j] = asrc[head * 64 + j * 16 + l16];
        adv[j] = adst[head * 64 + j * 16 + l16];
    }
    #pragma unroll
    for (int i = 0; i < 4; ++i) {
        #pragma unroll
        for (int r = 0; r < 4; ++r) {
            float ps = 0.f, pd = 0.f;
            #pragma unroll
            for (int j = 0; j < 4; ++j) {
                ps = fmaf(acc[i][j][r], asv[j], ps);
                pd = fmaf(acc[i][j][r], adv[j], pd);
            }
            #pragma unroll
            for (int o = 1; o < 16; o <<= 1) {
                ps += __shfl_xor(ps, o);
                pd += __shfl_xor(pd, o);
            }
            int row = brow + m_base + i * 16 + lquad * 4 + r;
            if (l16 == 0 && row < NNODES) {
                es[row * 4 + head] = ps;
                ed[row * 4 + head] = pd;
            }
        }
    }
}

// ---------------- aggregate: R0 gather structure (64-lane 4B coalesced row ----
// reads, 16-deep MLP) + 1-chunk-ahead software pipeline. Scalar chain
// (ssrc load -> es gather -> exp -> slot write) for chunk t+1 overlaps the
// 16 h-gathers of chunk t. Ping-pong LDS slots (per-wave, wave-synchronous).
// 2-deep ssrc register prefetch so the es gather for t+1 issues with no wait.

__global__ __launch_bounds__(256) void aggregate_kernel(const u8* __restrict__ h,
                                                        const int* __restrict__ ssrc,
                                                        const int* __restrict__ off,
                                                        const int* __restrict__ bsum,
                                                        const float* __restrict__ es,
                                                        const float* __restrict__ ed,
                                                        const float* __restrict__ bias,
                                                        u16* __restrict__ out,
                                                        int apply_elu) {
    __shared__ int2 xch[4][4][2][17];   // [wave][head][buf][16 slots + pad]
    const unsigned* h32 = (const unsigned*)h;   // 64 uints per row (σ-layout)
    int wid = threadIdx.x >> 6;
    int dst = blockIdx.x * 4 + wid;
    if (dst >= NNODES) return;
    int lane = threadIdx.x & 63;
    int head = lane >> 4;
    int j16 = lane & 15;
    int s = off[dst] + bsum[dst >> 8];
    int e = off[dst + 1] + bsum[(dst + 1) >> 8];
    float edh = ed[dst * 4 + head];

    float a0 = 0.f, a1 = 0.f, a2 = 0.f, a3 = 0.f, dpriv = 0.f;

    // prologue: chunk 0 scalars (every dst has >=1 edge: self-loop)
    {
        int cnt0 = e - s; if (cnt0 > 16) cnt0 = 16;
        int idx0 = s + j16; if (idx0 >= ETOT) idx0 = 0;
        int src0 = ssrc[idx0];
        float l = es[src0 * 4 + head] + edh;
        l = fmaxf(l, 0.2f * l);
        float ex0 = 0.f;
        if (j16 < cnt0) { ex0 = __expf(l); dpriv += ex0; }
        xch[wid][head][0][j16] = make_int2(src0, __float_as_int(ex0));
    }
    // prefetch chunk-1 ssrc into register
    int nidx = s + 16 + j16; if (nidx >= ETOT) nidx = 0;
    int nsrc = ssrc[nidx];

    int buf = 0;
    for (int base = s; base < e; base += 16) {
        int cur = e - base; if (cur > 16) cur = 16;
        int nbase = base + 16;
        // issue next-chunk es gather (nsrc already resident) + t+2 ssrc load
        float esv = es[(unsigned)nsrc * 4 + head];
        int n2idx = base + 32 + j16; if (n2idx >= ETOT) n2idx = 0;
        int n2src = ssrc[n2idx];
        // gather current chunk (16-deep independent MLP)
        const int2* slot = &xch[wid][head][buf][0];
        for (int j = 0; j < cur; ++j) {
            int2 pr = slot[j];
            float exj = __int_as_float(pr.y);
            unsigned hv = h32[(unsigned)pr.x * 64 + lane];
            f32x2 lo = __builtin_amdgcn_cvt_pk_f32_fp8(hv, false);
            f32x2 hi = __builtin_amdgcn_cvt_pk_f32_fp8(hv, true);
            a0 += lo.x * exj;
            a1 += lo.y * exj;
            a2 += hi.x * exj;
            a3 += hi.y * exj;
        }
        // finish next-chunk scalars: exp + slot write (values already landed)
        if (nbase < e) {
            int ncnt = e - nbase; if (ncnt > 16) ncnt = 16;
            float l = esv + edh;
            l = fmaxf(l, 0.2f * l);
            float nex = 0.f;
            if (j16 < ncnt) { nex = __expf(l); dpriv += nex; }
            xch[wid][head][buf ^ 1][j16] = make_int2(nsrc, __float_as_int(nex));
        }
        nsrc = n2src;
        buf ^= 1;
    }

    // denom: sum dpriv across the 16 lanes of this head group
    #pragma unroll
    for (int o = 1; o < 16; o <<= 1) dpriv += __shfl_xor(dpriv, o);
    float inv = 1.f / (dpriv + 1e-16f);
    // bias for stored positions lane*4+{0..3} = actual 64*(lane>>4)+(lane&15)+{0,16,32,48}
    int bbase = ((lane >> 4) << 6) | (lane & 15);
    float b0 = bias[bbase], b1 = bias[bbase + 16], b2 = bias[bbase + 32], b3 = bias[bbase + 48];
    float o0 = a0 * inv + b0;
    float o1 = a1 * inv + b1;
    float o2 = a2 * inv + b2;
    float o3 = a3 * inv + b3;
    if (apply_elu) {
        o0 = o0 > 0.f ? o0 : __expf(o0) - 1.f;
        o1 = o1 > 0.f ? o1 : __expf(o1) - 1.f;
        o2 = o2 > 0.f ? o2 : __expf(o2) - 1.f;
        o3 = o3 > 0.f ? o3 : __expf(o3) - 1.f;
    }
    ushort4 ov;
    ov.x = f2b(o0); ov.y = f2b(o1); ov.z = f2b(o2); ov.w = f2b(o3);
    *(ushort4*)(out + (size_t)dst * HC + lane * 4) = ov;
}

// ---------------- sliced mean-pool partials: block = (graph, 8 node-slices) ----------------

__global__ __launch_bounds__(256) void pool_kernel(const u16* __restrict__ hin,
                                                   const int* __restrict__ goff,
                                                   float* __restrict__ pp) {
    int g = blockIdx.x;
    int slice = blockIdx.y;            // 0..7
    int lane = threadIdx.x & 63;
    int wid = threadIdx.x >> 6;
    int s = goff[g], e = goff[g + 1];
    float a0 = 0.f, a1 = 0.f, a2 = 0.f, a3 = 0.f;
    for (int n = s + slice * 4 + wid; n < e; n += 32) {
        ushort4 hv = *(const ushort4*)(hin + (size_t)n * HC + lane * 4);
        a0 += b2f(hv.x); a1 += b2f(hv.y); a2 += b2f(hv.z); a3 += b2f(hv.w);
    }
    __shared__ float4 part[4][64];
    part[wid][lane] = make_float4(a0, a1, a2, a3);
    __syncthreads();
    if (wid == 0) {
        float4 p0 = part[0][lane], p1 = part[1][lane], p2 = part[2][lane], p3 = part[3][lane];
        float4 v = make_float4((p0.x + p1.x) + (p2.x + p3.x),
                               (p0.y + p1.y) + (p2.y + p3.y),
                               (p0.z + p1.z) + (p2.z + p3.z),
                               (p0.w + p1.w) + (p2.w + p3.w));
        *(float4*)(pp + ((size_t)(g * 8 + slice)) * HC + lane * 4) = v;
    }
}

// ---------------- final classifier: sum 8 slice-partials, mean, Wl dot ----------------

__global__ __launch_bounds__(64) void final_kernel(const float* __restrict__ pp,
                                                   const int* __restrict__ goff,
                                                   const float* __restrict__ Wl,
                                                   const float* __restrict__ bl,
                                                   float* __restrict__ out) {
    int g = blockIdx.x;
    int lane = threadIdx.x;
    float4 pv = make_float4(0.f, 0.f, 0.f, 0.f);
    #pragma unroll
    for (int sl = 0; sl < 8; ++sl) {
        float4 v = *(const float4*)(pp + ((size_t)(g * 8 + sl)) * HC + lane * 4);
        pv.x += v.x; pv.y += v.y; pv.z += v.z; pv.w += v.w;
    }
    float cntf = fmaxf((float)(goff[g + 1] - goff[g]), 1.f);
    float inv = 1.f / cntf;
    pv.x *= inv; pv.y *= inv; pv.z *= inv; pv.w *= inv;
    int wbase = ((lane >> 4) << 6) | (lane & 15);             // actual ch = wbase+{0,16,32,48}
    float acc[NOUT];
    #pragma unroll
    for (int o = 0; o < NOUT; ++o) {
        const float* w = Wl + o * HC + wbase;
        acc[o] = pv.x * w[0] + pv.y * w[16] + pv.z * w[32] + pv.w * w[48];
    }
    #pragma unroll
    for (int s = 32; s > 0; s >>= 1)
        #pragma unroll
        for (int o = 0; o < NOUT; ++o)
            acc[o] += __shfl_xor(acc[o], s);
    if (lane == 0) {
        #pragma unroll
        for (int o = 0; o < NOUT; ++o)
            out[g * NOUT + o] = acc[o] + bl[o];
    }
}

// ---------------- launch ----------------

extern "C" void kernel_launch(void* const* d_in, const int* in_sizes, int n_in,
                              void* d_out, int out_size, void* d_ws, size_t ws_size,
                              hipStream_t stream) {
    (void)in_sizes; (void)n_in; (void)out_size; (void)ws_size;
    const float* x   = (const float*)d_in[0];
    const int*   ei  = (const int*)d_in[1];
    const int*   bat = (const int*)d_in[2];
    const float* W1  = (const float*)d_in[3];
    const float* as1 = (const float*)d_in[4];
    const float* ad1 = (const float*)d_in[5];
    const float* b1  = (const float*)d_in[6];
    const float* W2  = (const float*)d_in[7];
    const float* as2 = (const float*)d_in[8];
    const float* ad2 = (const float*)d_in[9];
    const float* b2  = (const float*)d_in[10];
    const float* W3  = (const float*)d_in[11];
    const float* as3 = (const float*)d_in[12];
    const float* ad3 = (const float*)d_in[13];
    const float* b3  = (const float*)d_in[14];
    const float* Wl  = (const float*)d_in[15];
    const float* bl  = (const float*)d_in[16];
    float* out = (float*)d_out;

    char* ws = (char*)d_ws;
    size_t p = 0;
    auto alloc = [&](size_t bytes) {
        size_t a = p;
        p += (bytes + 255) & ~(size_t)255;
        return a;
    };
    int*      off  = (int*)(ws + alloc((size_t)(NB196 * 256 + 256) * 4));
    int*      bcur = (int*)(ws + alloc(256 * 4));
    int*      ssrc = (int*)(ws + alloc((size_t)ETOT * 4));
    unsigned* tmp  = (unsigned*)(ws + alloc((size_t)NB196 * BCAP * 4));
    int*      bsum = (int*)(ws + alloc(256 * 4));
    float*    es   = (float*)(ws + alloc((size_t)NNODES * NHEAD * 4));
    float*    ed   = (float*)(ws + alloc((size_t)NNODES * NHEAD * 4));
    u16*      xb   = (u16*)(ws + alloc((size_t)NNODES * FIN * 2));
    u16*      w1b  = (u16*)(ws + alloc((size_t)HC * FIN * 2));
    u16*      w2b  = (u16*)(ws + alloc((size_t)HC * HC * 2));
    u16*      w3b  = (u16*)(ws + alloc((size_t)HC * HC * 2));
    u8*       Hb   = (u8*)(ws + alloc((size_t)NNODES * HC));       // fp8 e4m3, σ-layout
    u16*      Ab   = (u16*)(ws + alloc((size_t)NNODES * HC * 2));  // bf16, σ-layout
    float*    pp   = (float*)(ws + alloc((size_t)NGRAPH * 8 * HC * 4));   // pool partials
    int*      goff = (int*)(ws + alloc((size_t)(NGRAPH + 1) * 4));
    alloc(128 * 1024);   // slack: gemm A-tile over-read past row NNODES stays in d_ws

    // zero only the 196 bucket counters
    hipMemsetAsync(bcur, 0, 256 * 4, stream);

    // bf16/σ conversions
    prep_kernel<<<NBCONV, 256, 0, stream>>>(x, W1, W2, W3, xb, w1b, w2b, w3b);

    // counting sort of edges by dst (fixed-capacity buckets; off derived in pass 2)
    scatter1_kernel<<<NBS1, 256, 0, stream>>>(ei, bcur, tmp);
    scanb_kernel<<<1, 256, 0, stream>>>(bcur, bsum, bat, goff);
    scatter2_kernel<<<NB196, 256, 0, stream>>>(tmp, bcur, bsum, off, ssrc);

    dim3 ggrid((NNODES + TBM - 1) / TBM, HC / TBN);
    int nblocks4 = (NNODES + 3) / 4;

    // layer 1
    gemm_mfma<<<ggrid, 256, 0, stream>>>(xb, w1b, Hb, FIN, as1, ad1, es, ed);
    aggregate_kernel<<<nblocks4, 256, 0, stream>>>(Hb, ssrc, off, bsum, es, ed, b1, Ab, 1);
    // layer 2
    gemm_mfma<<<ggrid, 256, 0, stream>>>(Ab, w2b, Hb, HC, as2, ad2, es, ed);
    aggregate_kernel<<<nblocks4, 256, 0, stream>>>(Hb, ssrc, off, bsum, es, ed, b2, Ab, 1);
    // layer 3
    gemm_mfma<<<ggrid, 256, 0, stream>>>(Ab, w3b, Hb, HC, as3, ad3, es, ed);
    aggregate_kernel<<<nblocks4, 256, 0, stream>>>(Hb, ssrc, off, bsum, es, ed, b3, Ab, 0);

    // pool + classify
    dim3 pgrid(NGRAPH, 8);
    pool_kernel<<<pgrid, 256, 0, stream>>>(Ab, goff, pp);
    final_kernel<<<NGRAPH, 64, 0, stream>>>(pp, goff, Wl, bl, out);
}